// Round 8
// baseline (2458.540 us; speedup 1.0000x reference)
//
#include <hip/hip_runtime.h>

#define FPS_N 32768
#define FPS_T 256          // threads per block
#define NBLK 4             // blocks per batch
#define PPB (FPS_N / NBLK) // 8192 points per block
#define PPT (PPB / FPS_T)  // 32 points per thread
#define NCH (PPT / 4)      // 8 four-point chunks per thread
#define NQ 256
#define DD 256
#define NT 64              // n-tile for MLP kernel
#define B_BATCH 64

// d_ws layout: gmax u64[64][256] (128 KB) | fcount int[64][256] (64 KB)
#define WS_GMAX_BYTES (B_BATCH * NQ * 8)
#define WS_CLEAR_BYTES (B_BATCH * NQ * 8 + B_BATCH * NQ * 4)

// ---------------------------------------------------------------------------
// Kernel 1: furthest point sampling, FOUR blocks (256 thr) per batch.
// R2-R7 lesson: per-thread VGPR cap = 65536/blocksize (one workgroup can only
// reach HALF the 512KB/CU register file), so coords(384KB)+dist(128KB) can
// never be resident for a single block -> split the cloud over 4 CUs.
// Each block: 8192 pts, coords 24xfloat4=96 VGPR + dist 8xfloat4=32 VGPR,
// all register-resident, ZERO per-iteration memory streaming.
// Cross-block argmax per round: u64 atomicMax of (distbits<<32 | ~idx)
// (monotonic for f32>=0; ~idx -> ties pick smallest index = jnp.argmax),
// then release fetch_add on a per-round counter; spin-acquire until 4.
// Per-round-unique slots, d_ws memset at launch -> deterministic replays.
// Block->(batch,quarter) swizzle keeps a batch's 4 blocks on one XCD.
// Arithmetic matches numpy bitwise: sub, mul, add (no FMA), fminf.
// ---------------------------------------------------------------------------
__global__ __attribute__((amdgpu_flat_work_group_size(FPS_T, FPS_T)))
void fps_kernel(const float* __restrict__ xyz, float* __restrict__ qout,
                unsigned long long* __restrict__ gmax,
                int* __restrict__ fcount) {
  const int gid = blockIdx.x;
  const int xcd = gid & 7;          // round-robin dispatch: block i -> XCD i%8
  const int s = gid >> 3;
  const int b = xcd + 8 * (s >> 2); // all 4 quarters of batch b on same XCD
  const int q = s & 3;
  const int t = threadIdx.x;

  const float* __restrict__ base = xyz + (size_t)b * (FPS_N * 3);
  const float4* __restrict__ base4 =
      (const float4*)(base + (size_t)q * PPB * 3) + (size_t)t * (PPT * 3 / 4);
  float* qb = qout + (size_t)b * (NQ * 3);

  __shared__ float2 red[FPS_T / 64];
  __shared__ float4 bc;   // broadcast: cx, cy, cz

  // persistent registers: coords 24 float4 = 96 VGPR, dist 8 float4 = 32 VGPR
  float4 C[PPT * 3 / 4];
#pragma unroll
  for (int i = 0; i < PPT * 3 / 4; ++i) C[i] = base4[i];
  float4 Dst[NCH];
#pragma unroll
  for (int c = 0; c < NCH; ++c) Dst[c] = make_float4(1e10f, 1e10f, 1e10f, 1e10f);

  if (q == 0 && t == 0) { qb[0] = base[0]; qb[1] = base[1]; qb[2] = base[2]; }
  float cx = base[0], cy = base[1], cz = base[2];   // inds[0] == 0

#pragma unroll 1
  for (int j = 1; j < NQ; ++j) {
    float best = -1.0f;
    int bik = 0;

#pragma unroll
    for (int c = 0; c < NCH; ++c) {
      const float4 a4 = C[3 * c + 0];
      const float4 b4 = C[3 * c + 1];
      const float4 c4 = C[3 * c + 2];
      // unpack 12 floats -> 4 points (register renaming, no real ops)
      const float px[4] = {a4.x, a4.w, b4.z, c4.y};
      const float py[4] = {a4.y, b4.x, b4.w, c4.z};
      const float pz[4] = {a4.z, b4.y, c4.x, c4.w};
      const float dold[4] = {Dst[c].x, Dst[c].y, Dst[c].z, Dst[c].w};
      float dnew[4];
#pragma unroll
      for (int i = 0; i < 4; ++i) {
        const float dx = __fsub_rn(px[i], cx);
        const float dy = __fsub_rn(py[i], cy);
        const float dz = __fsub_rn(pz[i], cz);
        // numpy order: (dx^2 + dy^2) + dz^2, no fma
        const float d = __fadd_rn(__fadd_rn(__fmul_rn(dx, dx), __fmul_rn(dy, dy)),
                                  __fmul_rn(dz, dz));
        const float nd = fminf(dold[i], d);
        dnew[i] = nd;
        if (nd > best) { best = nd; bik = c * 4 + i; }  // strict >: first occ.
      }
      Dst[c] = make_float4(dnew[0], dnew[1], dnew[2], dnew[3]);
    }
    int bi = q * PPB + t * PPT + bik;   // global point index

    // wave (64-lane) argmax reduce with first-index tie-break
#pragma unroll
    for (int off = 32; off; off >>= 1) {
      const float ov = __shfl_xor(best, off);
      const int oi = __shfl_xor(bi, off);
      if (ov > best || (ov == best && oi < bi)) { best = ov; bi = oi; }
    }
    if ((t & 63) == 0) red[t >> 6] = make_float2(best, __int_as_float(bi));
    __syncthreads();

    if (t == 0) {
      float fv = red[0].x;
      int fi = __float_as_int(red[0].y);
#pragma unroll
      for (int w = 1; w < FPS_T / 64; ++w) {
        const float ov = red[w].x;
        const int oi = __float_as_int(red[w].y);
        if (ov > fv || (ov == fv && oi < fi)) { fv = ov; fi = oi; }
      }
      // cross-block combine: monotonic u64 pack (f32>=0), ~idx for ties
      const int slot = b * NQ + j;
      const unsigned long long pack =
          ((unsigned long long)(unsigned int)__float_as_int(fv) << 32) |
          (unsigned int)~(unsigned int)fi;
      __hip_atomic_fetch_max(&gmax[slot], pack, __ATOMIC_RELEASE,
                             __HIP_MEMORY_SCOPE_AGENT);
      __hip_atomic_fetch_add(&fcount[slot], 1, __ATOMIC_RELEASE,
                             __HIP_MEMORY_SCOPE_AGENT);
      while (__hip_atomic_load(&fcount[slot], __ATOMIC_ACQUIRE,
                               __HIP_MEMORY_SCOPE_AGENT) < NBLK) {
        __builtin_amdgcn_s_sleep(1);
      }
      const unsigned long long g = __hip_atomic_load(
          &gmax[slot], __ATOMIC_ACQUIRE, __HIP_MEMORY_SCOPE_AGENT);
      const int gi = (int)~(unsigned int)(g & 0xffffffffull);
      // fetch new centroid (same-address broadcast, L2-hot)
      const float* cp = base + 3 * (size_t)gi;
      const float ncx = cp[0], ncy = cp[1], ncz = cp[2];
      bc = make_float4(ncx, ncy, ncz, 0.f);
      if (q == 0) { qb[3 * j + 0] = ncx; qb[3 * j + 1] = ncy; qb[3 * j + 2] = ncz; }
    }
    __syncthreads();
    cx = bc.x; cy = bc.y; cz = bc.z;
  }
}

// ---------------------------------------------------------------------------
// Kernel 2: fourier positional embedding + 2-layer MLP, fused. (unchanged)
// ---------------------------------------------------------------------------
__global__ __launch_bounds__(256) void embed_mlp_kernel(
    const float* __restrict__ qxyz, const float* __restrict__ pcmin,
    const float* __restrict__ pcmax, const float* __restrict__ G,
    const float* __restrict__ W1, const float* __restrict__ b1,
    const float* __restrict__ W2, const float* __restrict__ b2,
    float* __restrict__ out) {
  const int b = blockIdx.x >> 2;
  const int n0 = (blockIdx.x & 3) * NT;
  const int tid = threadIdx.x;
  const int ty = tid >> 4, tx = tid & 15;

  __shared__ __align__(16) float P[DD][NT + 4];   // pos
  __shared__ __align__(16) float H[DD][NT + 4];   // hidden
  __shared__ __align__(16) float Wl[64][NT + 4];  // W tile (transposed)
  __shared__ float snorm[NT][3];

  if (tid < NT) {
    const int n = n0 + tid;
    const float qx = qxyz[(size_t)b * (NQ * 3) + 3 * n + 0];
    const float qy = qxyz[(size_t)b * (NQ * 3) + 3 * n + 1];
    const float qz = qxyz[(size_t)b * (NQ * 3) + 3 * n + 2];
    snorm[tid][0] = (qx - pcmin[3 * b + 0]) / (pcmax[3 * b + 0] - pcmin[3 * b + 0]);
    snorm[tid][1] = (qy - pcmin[3 * b + 1]) / (pcmax[3 * b + 1] - pcmin[3 * b + 1]);
    snorm[tid][2] = (qz - pcmin[3 * b + 2]) / (pcmax[3 * b + 2] - pcmin[3 * b + 2]);
  }
  __syncthreads();

  {
    const int nn = tid & 63;
    const int fg = tid >> 6;   // 0..3
    const float nx = snorm[nn][0], ny = snorm[nn][1], nz = snorm[nn][2];
#pragma unroll 4
    for (int ff = 0; ff < 32; ++ff) {
      const int f = fg * 32 + ff;
      const float s = nx * G[f] + ny * G[128 + f] + nz * G[256 + f];
      const float proj = 6.28318530717958647692f * s;
      P[f][nn] = sinf(proj);
      P[f + 128][nn] = cosf(proj);
    }
  }

  for (int layer = 0; layer < 2; ++layer) {
    const float* W = layer ? W2 : W1;
    const float* bias = layer ? b2 : b1;
    const float (*src)[NT + 4] = layer ? H : P;

    for (int dt = 0; dt < 4; ++dt) {
      float acc[4][4] = {};
      for (int kt = 0; kt < 4; ++kt) {
        __syncthreads();
        {  // stage W tile transposed: Wl[c][d] = W[dt*64+d][kt*64+c]
          const int r = tid >> 2;
          const int cb = (tid & 3) * 16;
          const float* wrow = W + (size_t)(dt * 64 + r) * DD + kt * 64 + cb;
#pragma unroll
          for (int i = 0; i < 4; ++i) {
            const float4 v = *(const float4*)(wrow + 4 * i);
            Wl[cb + 4 * i + 0][r] = v.x;
            Wl[cb + 4 * i + 1][r] = v.y;
            Wl[cb + 4 * i + 2][r] = v.z;
            Wl[cb + 4 * i + 3][r] = v.w;
          }
        }
        __syncthreads();
#pragma unroll 8
        for (int cc = 0; cc < 64; ++cc) {
          const float4 a = *(const float4*)&Wl[cc][ty * 4];
          const float4 p4 = *(const float4*)&src[kt * 64 + cc][tx * 4];
          acc[0][0] = fmaf(a.x, p4.x, acc[0][0]);
          acc[0][1] = fmaf(a.x, p4.y, acc[0][1]);
          acc[0][2] = fmaf(a.x, p4.z, acc[0][2]);
          acc[0][3] = fmaf(a.x, p4.w, acc[0][3]);
          acc[1][0] = fmaf(a.y, p4.x, acc[1][0]);
          acc[1][1] = fmaf(a.y, p4.y, acc[1][1]);
          acc[1][2] = fmaf(a.y, p4.z, acc[1][2]);
          acc[1][3] = fmaf(a.y, p4.w, acc[1][3]);
          acc[2][0] = fmaf(a.z, p4.x, acc[2][0]);
          acc[2][1] = fmaf(a.z, p4.y, acc[2][1]);
          acc[2][2] = fmaf(a.z, p4.z, acc[2][2]);
          acc[2][3] = fmaf(a.z, p4.w, acc[2][3]);
          acc[3][0] = fmaf(a.w, p4.x, acc[3][0]);
          acc[3][1] = fmaf(a.w, p4.y, acc[3][1]);
          acc[3][2] = fmaf(a.w, p4.z, acc[3][2]);
          acc[3][3] = fmaf(a.w, p4.w, acc[3][3]);
        }
      }
      if (layer == 0) {
#pragma unroll
        for (int i = 0; i < 4; ++i) {
          const float bv = bias[dt * 64 + ty * 4 + i];
          float4 h;
          h.x = fmaxf(acc[i][0] + bv, 0.f);
          h.y = fmaxf(acc[i][1] + bv, 0.f);
          h.z = fmaxf(acc[i][2] + bv, 0.f);
          h.w = fmaxf(acc[i][3] + bv, 0.f);
          *(float4*)&H[dt * 64 + ty * 4 + i][tx * 4] = h;
        }
      } else {
        float* ob = out + (size_t)b * (DD * NQ);
#pragma unroll
        for (int i = 0; i < 4; ++i) {
          const float bv = bias[dt * 64 + ty * 4 + i];
          float4 h;
          h.x = fmaxf(acc[i][0] + bv, 0.f);
          h.y = fmaxf(acc[i][1] + bv, 0.f);
          h.z = fmaxf(acc[i][2] + bv, 0.f);
          h.w = fmaxf(acc[i][3] + bv, 0.f);
          *(float4*)(ob + (size_t)(dt * 64 + ty * 4 + i) * NQ + n0 + tx * 4) = h;
        }
      }
    }
  }
}

extern "C" void kernel_launch(void* const* d_in, const int* in_sizes, int n_in,
                              void* d_out, int out_size, void* d_ws, size_t ws_size,
                              hipStream_t stream) {
  (void)in_sizes; (void)n_in; (void)ws_size; (void)out_size;
  const float* xyz   = (const float*)d_in[0];
  const float* pcmin = (const float*)d_in[1];
  const float* pcmax = (const float*)d_in[2];
  const float* G     = (const float*)d_in[3];
  const float* W1    = (const float*)d_in[4];
  const float* b1    = (const float*)d_in[5];
  const float* W2    = (const float*)d_in[6];
  const float* b2    = (const float*)d_in[7];

  float* qxyz  = (float*)d_out;                       // [64][256][3]
  float* embed = qxyz + (size_t)B_BATCH * NQ * 3;     // [64][256][256]

  unsigned long long* gmax = (unsigned long long*)d_ws;
  int* fcount = (int*)((char*)d_ws + WS_GMAX_BYTES);

  // clear sync state every launch (deterministic across graph replays)
  hipMemsetAsync(d_ws, 0, WS_CLEAR_BYTES, stream);

  hipLaunchKernelGGL(fps_kernel, dim3(B_BATCH * NBLK), dim3(FPS_T), 0, stream,
                     xyz, qxyz, gmax, fcount);
  hipLaunchKernelGGL(embed_mlp_kernel, dim3(B_BATCH * 4), dim3(256), 0, stream,
                     qxyz, pcmin, pcmax, G, W1, b1, W2, b2, embed);
}

// Round 9
// 631.314 us; speedup vs baseline: 3.8943x; 3.8943x over previous
//
#include <hip/hip_runtime.h>

#define FPS_N 32768
#define FPS_T 256          // threads per block
#define NBLK 4             // blocks per batch
#define PPB (FPS_N / NBLK) // 8192 points per block
#define PPT (PPB / FPS_T)  // 32 points per thread
#define NCH (PPT / 4)      // 8 four-point chunks per thread
#define NQ 256
#define DD 256
#define NT 64              // n-tile for MLP kernel
#define B_BATCH 64

// d_ws: u64 slot[64][256][4] = 512 KB, zeroed per launch
#define WS_CLEAR_BYTES (B_BATCH * NQ * NBLK * 8)

// ---------------------------------------------------------------------------
// Kernel 1: furthest point sampling, FOUR blocks (256 thr) per batch.
// Everything register-resident per block: coords 24xfloat4 = 96 VGPR +
// dist 8xfloat4 = 32 VGPR (~150 total; waves_per_eu(1) makes the allocator
// grant 256 as proven in R6 — R8 regression was dropping this attribute).
// Cross-block combine per round: ONE relaxed u64 store per block into its
// own slot (pack = distbits<<32 | ~idx: monotone for f32>=0, ~idx gives
// smallest-index tie-break = jnp.argmax), then wave-0 lanes 0-3 poll the 4
// slots in parallel and butterfly-max. Store-before-poll => deadlock-free.
// At 256 VGPR, 2 blocks/CU still fit physically -> co-residency guaranteed.
// Arithmetic matches numpy bitwise: sub, mul, add (no FMA), fminf.
// ---------------------------------------------------------------------------
__global__ __attribute__((amdgpu_flat_work_group_size(FPS_T, FPS_T),
                          amdgpu_waves_per_eu(1)))
void fps_kernel(const float* __restrict__ xyz, float* __restrict__ qout,
                unsigned long long* __restrict__ gslot) {
  const int gid = blockIdx.x;
  const int xcd = gid & 7;          // round-robin dispatch: block i -> XCD i%8
  const int s = gid >> 3;
  const int b = xcd + 8 * (s >> 2); // all 4 quarters of batch b on same XCD
  const int q = s & 3;
  const int t = threadIdx.x;

  const float* __restrict__ base = xyz + (size_t)b * (FPS_N * 3);
  const float4* __restrict__ base4 =
      (const float4*)(base + (size_t)q * PPB * 3) + (size_t)t * (PPT * 3 / 4);
  float* qb = qout + (size_t)b * (NQ * 3);
  unsigned long long* bslot = gslot + (size_t)b * (NQ * NBLK);

  __shared__ unsigned long long sred[FPS_T / 64];
  __shared__ float4 bc;   // broadcast: cx, cy, cz

  // persistent registers: coords 24 float4 = 96 VGPR, dist 8 float4 = 32 VGPR
  float4 C[PPT * 3 / 4];
#pragma unroll
  for (int i = 0; i < PPT * 3 / 4; ++i) C[i] = base4[i];
  float4 Dst[NCH];
#pragma unroll
  for (int c = 0; c < NCH; ++c) Dst[c] = make_float4(1e10f, 1e10f, 1e10f, 1e10f);

  if (q == 0 && t == 0) { qb[0] = base[0]; qb[1] = base[1]; qb[2] = base[2]; }
  float cx = base[0], cy = base[1], cz = base[2];   // inds[0] == 0

#pragma unroll 1
  for (int j = 1; j < NQ; ++j) {
    float best = -1.0f;
    int bik = 0;

#pragma unroll
    for (int c = 0; c < NCH; ++c) {
      const float4 a4 = C[3 * c + 0];
      const float4 b4 = C[3 * c + 1];
      const float4 c4 = C[3 * c + 2];
      // unpack 12 floats -> 4 points (register renaming, no real ops)
      const float px[4] = {a4.x, a4.w, b4.z, c4.y};
      const float py[4] = {a4.y, b4.x, b4.w, c4.z};
      const float pz[4] = {a4.z, b4.y, c4.x, c4.w};
      const float dold[4] = {Dst[c].x, Dst[c].y, Dst[c].z, Dst[c].w};
      float dnew[4];
#pragma unroll
      for (int i = 0; i < 4; ++i) {
        const float dx = __fsub_rn(px[i], cx);
        const float dy = __fsub_rn(py[i], cy);
        const float dz = __fsub_rn(pz[i], cz);
        // numpy order: (dx^2 + dy^2) + dz^2, no fma
        const float d = __fadd_rn(__fadd_rn(__fmul_rn(dx, dx), __fmul_rn(dy, dy)),
                                  __fmul_rn(dz, dz));
        const float nd = fminf(dold[i], d);
        dnew[i] = nd;
        if (nd > best) { best = nd; bik = c * 4 + i; }  // strict >: first occ.
      }
      Dst[c] = make_float4(dnew[0], dnew[1], dnew[2], dnew[3]);
    }
    int bi = q * PPB + t * PPT + bik;   // global point index

    // wave (64-lane) argmax reduce with first-index tie-break
#pragma unroll
    for (int off = 32; off; off >>= 1) {
      const float ov = __shfl_xor(best, off);
      const int oi = __shfl_xor(bi, off);
      if (ov > best || (ov == best && oi < bi)) { best = ov; bi = oi; }
    }
    // pack: monotone in dist (f32>=0), ~idx -> max picks smallest index
    if ((t & 63) == 0) {
      sred[t >> 6] = ((unsigned long long)(unsigned int)__float_as_int(best) << 32) |
                     (unsigned int)~(unsigned int)bi;
    }
    __syncthreads();

    if (t < 64) {   // wave 0 handles block combine + cross-block sync
      unsigned long long p = sred[t & 3];
#pragma unroll
      for (int off = 1; off < 4; off <<= 1) {
        const unsigned long long o = __shfl_xor(p, off);
        if (o > p) p = o;
      }
      // p = this block's pack (identical in lanes 0-3)
      if (t == 0) {
        __hip_atomic_store(&bslot[j * NBLK + q], p, __ATOMIC_RELAXED,
                           __HIP_MEMORY_SCOPE_AGENT);
      }
      unsigned long long rp = 0;
      if (t < NBLK) {
        do {
          rp = __hip_atomic_load(&bslot[j * NBLK + t], __ATOMIC_RELAXED,
                                 __HIP_MEMORY_SCOPE_AGENT);
        } while (rp == 0ull);
      }
#pragma unroll
      for (int off = 1; off < 4; off <<= 1) {
        const unsigned long long o = __shfl_xor(rp, off);
        if (o > rp) rp = o;
      }
      if (t == 0) {
        const int gi = (int)~(unsigned int)(rp & 0xffffffffull);
        const float* cp = base + 3 * (size_t)gi;
        const float ncx = cp[0], ncy = cp[1], ncz = cp[2];
        bc = make_float4(ncx, ncy, ncz, 0.f);
        if (q == 0) { qb[3 * j + 0] = ncx; qb[3 * j + 1] = ncy; qb[3 * j + 2] = ncz; }
      }
    }
    __syncthreads();
    cx = bc.x; cy = bc.y; cz = bc.z;
  }
}

// ---------------------------------------------------------------------------
// Kernel 2: fourier positional embedding + 2-layer MLP, fused. (unchanged)
// ---------------------------------------------------------------------------
__global__ __launch_bounds__(256) void embed_mlp_kernel(
    const float* __restrict__ qxyz, const float* __restrict__ pcmin,
    const float* __restrict__ pcmax, const float* __restrict__ G,
    const float* __restrict__ W1, const float* __restrict__ b1,
    const float* __restrict__ W2, const float* __restrict__ b2,
    float* __restrict__ out) {
  const int b = blockIdx.x >> 2;
  const int n0 = (blockIdx.x & 3) * NT;
  const int tid = threadIdx.x;
  const int ty = tid >> 4, tx = tid & 15;

  __shared__ __align__(16) float P[DD][NT + 4];   // pos
  __shared__ __align__(16) float H[DD][NT + 4];   // hidden
  __shared__ __align__(16) float Wl[64][NT + 4];  // W tile (transposed)
  __shared__ float snorm[NT][3];

  if (tid < NT) {
    const int n = n0 + tid;
    const float qx = qxyz[(size_t)b * (NQ * 3) + 3 * n + 0];
    const float qy = qxyz[(size_t)b * (NQ * 3) + 3 * n + 1];
    const float qz = qxyz[(size_t)b * (NQ * 3) + 3 * n + 2];
    snorm[tid][0] = (qx - pcmin[3 * b + 0]) / (pcmax[3 * b + 0] - pcmin[3 * b + 0]);
    snorm[tid][1] = (qy - pcmin[3 * b + 1]) / (pcmax[3 * b + 1] - pcmin[3 * b + 1]);
    snorm[tid][2] = (qz - pcmin[3 * b + 2]) / (pcmax[3 * b + 2] - pcmin[3 * b + 2]);
  }
  __syncthreads();

  {
    const int nn = tid & 63;
    const int fg = tid >> 6;   // 0..3
    const float nx = snorm[nn][0], ny = snorm[nn][1], nz = snorm[nn][2];
#pragma unroll 4
    for (int ff = 0; ff < 32; ++ff) {
      const int f = fg * 32 + ff;
      const float s = nx * G[f] + ny * G[128 + f] + nz * G[256 + f];
      const float proj = 6.28318530717958647692f * s;
      P[f][nn] = sinf(proj);
      P[f + 128][nn] = cosf(proj);
    }
  }

  for (int layer = 0; layer < 2; ++layer) {
    const float* W = layer ? W2 : W1;
    const float* bias = layer ? b2 : b1;
    const float (*src)[NT + 4] = layer ? H : P;

    for (int dt = 0; dt < 4; ++dt) {
      float acc[4][4] = {};
      for (int kt = 0; kt < 4; ++kt) {
        __syncthreads();
        {  // stage W tile transposed: Wl[c][d] = W[dt*64+d][kt*64+c]
          const int r = tid >> 2;
          const int cb = (tid & 3) * 16;
          const float* wrow = W + (size_t)(dt * 64 + r) * DD + kt * 64 + cb;
#pragma unroll
          for (int i = 0; i < 4; ++i) {
            const float4 v = *(const float4*)(wrow + 4 * i);
            Wl[cb + 4 * i + 0][r] = v.x;
            Wl[cb + 4 * i + 1][r] = v.y;
            Wl[cb + 4 * i + 2][r] = v.z;
            Wl[cb + 4 * i + 3][r] = v.w;
          }
        }
        __syncthreads();
#pragma unroll 8
        for (int cc = 0; cc < 64; ++cc) {
          const float4 a = *(const float4*)&Wl[cc][ty * 4];
          const float4 p4 = *(const float4*)&src[kt * 64 + cc][tx * 4];
          acc[0][0] = fmaf(a.x, p4.x, acc[0][0]);
          acc[0][1] = fmaf(a.x, p4.y, acc[0][1]);
          acc[0][2] = fmaf(a.x, p4.z, acc[0][2]);
          acc[0][3] = fmaf(a.x, p4.w, acc[0][3]);
          acc[1][0] = fmaf(a.y, p4.x, acc[1][0]);
          acc[1][1] = fmaf(a.y, p4.y, acc[1][1]);
          acc[1][2] = fmaf(a.y, p4.z, acc[1][2]);
          acc[1][3] = fmaf(a.y, p4.w, acc[1][3]);
          acc[2][0] = fmaf(a.z, p4.x, acc[2][0]);
          acc[2][1] = fmaf(a.z, p4.y, acc[2][1]);
          acc[2][2] = fmaf(a.z, p4.z, acc[2][2]);
          acc[2][3] = fmaf(a.z, p4.w, acc[2][3]);
          acc[3][0] = fmaf(a.w, p4.x, acc[3][0]);
          acc[3][1] = fmaf(a.w, p4.y, acc[3][1]);
          acc[3][2] = fmaf(a.w, p4.z, acc[3][2]);
          acc[3][3] = fmaf(a.w, p4.w, acc[3][3]);
        }
      }
      if (layer == 0) {
#pragma unroll
        for (int i = 0; i < 4; ++i) {
          const float bv = bias[dt * 64 + ty * 4 + i];
          float4 h;
          h.x = fmaxf(acc[i][0] + bv, 0.f);
          h.y = fmaxf(acc[i][1] + bv, 0.f);
          h.z = fmaxf(acc[i][2] + bv, 0.f);
          h.w = fmaxf(acc[i][3] + bv, 0.f);
          *(float4*)&H[dt * 64 + ty * 4 + i][tx * 4] = h;
        }
      } else {
        float* ob = out + (size_t)b * (DD * NQ);
#pragma unroll
        for (int i = 0; i < 4; ++i) {
          const float bv = bias[dt * 64 + ty * 4 + i];
          float4 h;
          h.x = fmaxf(acc[i][0] + bv, 0.f);
          h.y = fmaxf(acc[i][1] + bv, 0.f);
          h.z = fmaxf(acc[i][2] + bv, 0.f);
          h.w = fmaxf(acc[i][3] + bv, 0.f);
          *(float4*)(ob + (size_t)(dt * 64 + ty * 4 + i) * NQ + n0 + tx * 4) = h;
        }
      }
    }
  }
}

extern "C" void kernel_launch(void* const* d_in, const int* in_sizes, int n_in,
                              void* d_out, int out_size, void* d_ws, size_t ws_size,
                              hipStream_t stream) {
  (void)in_sizes; (void)n_in; (void)ws_size; (void)out_size;
  const float* xyz   = (const float*)d_in[0];
  const float* pcmin = (const float*)d_in[1];
  const float* pcmax = (const float*)d_in[2];
  const float* G     = (const float*)d_in[3];
  const float* W1    = (const float*)d_in[4];
  const float* b1    = (const float*)d_in[5];
  const float* W2    = (const float*)d_in[6];
  const float* b2    = (const float*)d_in[7];

  float* qxyz  = (float*)d_out;                       // [64][256][3]
  float* embed = qxyz + (size_t)B_BATCH * NQ * 3;     // [64][256][256]

  unsigned long long* gslot = (unsigned long long*)d_ws;

  // clear sync slots every launch (deterministic across graph replays)
  hipMemsetAsync(d_ws, 0, WS_CLEAR_BYTES, stream);

  hipLaunchKernelGGL(fps_kernel, dim3(B_BATCH * NBLK), dim3(FPS_T), 0, stream,
                     xyz, qxyz, gslot);
  hipLaunchKernelGGL(embed_mlp_kernel, dim3(B_BATCH * 4), dim3(256), 0, stream,
                     qxyz, pcmin, pcmax, G, W1, b1, W2, b2, embed);
}

// Round 10
// 628.000 us; speedup vs baseline: 3.9149x; 1.0053x over previous
//
#include <hip/hip_runtime.h>

#define FPS_N 32768
#define FPS_T 256          // threads per block
#define NBLK 4             // blocks per batch
#define PPB (FPS_N / NBLK) // 8192 points per block
#define PPT (PPB / FPS_T)  // 32 points per thread
#define NCH (PPT / 4)      // 8 four-point chunks per thread
#define NQ 256
#define DD 256
#define NT 64              // n-tile for MLP kernel
#define B_BATCH 64

// d_ws: u64 slot[64][256][4] = 512 KB, zeroed per launch
#define WS_CLEAR_BYTES (B_BATCH * NQ * NBLK * 8)

// ---------------------------------------------------------------------------
// Kernel 1: furthest point sampling, FOUR blocks (256 thr) per batch.
// Coords register-resident and PINNED: after the one-time load, an empty
// asm "+v" on every component makes rematerialization illegal — R9 showed
// the compiler otherwise re-reads base4[] from L2 every iteration (VGPR=76,
// remat+spill, 2.1us/iter). Demand ~155 VGPR < the 65536/blocksize=256 cap
// observed consistently in R2-R9 for 256-thread blocks.
// Cross-block combine per round: ONE relaxed u64 store per block into its
// own slot (pack = distbits<<32 | ~idx: monotone for f32>=0, ~idx gives
// smallest-index tie-break = jnp.argmax), wave-0 lanes 0-3 poll the 4 slots
// in parallel, butterfly-max. Store-before-poll => deadlock-free; 256 blocks
// on 256 CUs co-resident (at ~160 VGPR many blocks/CU fit physically).
// Arithmetic matches numpy bitwise: sub, mul, add (no FMA), fminf.
// ---------------------------------------------------------------------------
__global__ __attribute__((amdgpu_flat_work_group_size(FPS_T, FPS_T),
                          amdgpu_waves_per_eu(1)))
void fps_kernel(const float* __restrict__ xyz, float* __restrict__ qout,
                unsigned long long* __restrict__ gslot) {
  const int gid = blockIdx.x;
  const int xcd = gid & 7;          // round-robin dispatch: block i -> XCD i%8
  const int s = gid >> 3;
  const int b = xcd + 8 * (s >> 2); // all 4 quarters of batch b on same XCD
  const int q = s & 3;
  const int t = threadIdx.x;

  const float* __restrict__ base = xyz + (size_t)b * (FPS_N * 3);
  const float4* __restrict__ base4 =
      (const float4*)(base + (size_t)q * PPB * 3) + (size_t)t * (PPT * 3 / 4);
  float* qb = qout + (size_t)b * (NQ * 3);
  unsigned long long* bslot = gslot + (size_t)b * (NQ * NBLK);

  __shared__ unsigned long long sred[FPS_T / 64];
  __shared__ float4 bc;   // broadcast: cx, cy, cz

  // persistent registers: coords 24 float4 = 96 VGPR, dist 8 float4 = 32 VGPR
  float4 C[PPT * 3 / 4];
#pragma unroll
  for (int i = 0; i < PPT * 3 / 4; ++i) C[i] = base4[i];
  // PIN: forbid rematerialization of the loads (the R9 failure mode)
#pragma unroll
  for (int i = 0; i < PPT * 3 / 4; ++i) {
    asm volatile("" : "+v"(C[i].x), "+v"(C[i].y), "+v"(C[i].z), "+v"(C[i].w));
  }
  float4 Dst[NCH];
#pragma unroll
  for (int c = 0; c < NCH; ++c) Dst[c] = make_float4(1e10f, 1e10f, 1e10f, 1e10f);

  if (q == 0 && t == 0) { qb[0] = base[0]; qb[1] = base[1]; qb[2] = base[2]; }
  float cx = base[0], cy = base[1], cz = base[2];   // inds[0] == 0

#pragma unroll 1
  for (int j = 1; j < NQ; ++j) {
    float best = -1.0f;
    int bik = 0;

#pragma unroll
    for (int c = 0; c < NCH; ++c) {
      const float4 a4 = C[3 * c + 0];
      const float4 b4 = C[3 * c + 1];
      const float4 c4 = C[3 * c + 2];
      // unpack 12 floats -> 4 points (register renaming, no real ops)
      const float px[4] = {a4.x, a4.w, b4.z, c4.y};
      const float py[4] = {a4.y, b4.x, b4.w, c4.z};
      const float pz[4] = {a4.z, b4.y, c4.x, c4.w};
      const float dold[4] = {Dst[c].x, Dst[c].y, Dst[c].z, Dst[c].w};
      float dnew[4];
#pragma unroll
      for (int i = 0; i < 4; ++i) {
        const float dx = __fsub_rn(px[i], cx);
        const float dy = __fsub_rn(py[i], cy);
        const float dz = __fsub_rn(pz[i], cz);
        // numpy order: (dx^2 + dy^2) + dz^2, no fma
        const float d = __fadd_rn(__fadd_rn(__fmul_rn(dx, dx), __fmul_rn(dy, dy)),
                                  __fmul_rn(dz, dz));
        const float nd = fminf(dold[i], d);
        dnew[i] = nd;
        if (nd > best) { best = nd; bik = c * 4 + i; }  // strict >: first occ.
      }
      Dst[c] = make_float4(dnew[0], dnew[1], dnew[2], dnew[3]);
    }
    int bi = q * PPB + t * PPT + bik;   // global point index

    // wave (64-lane) argmax reduce with first-index tie-break
#pragma unroll
    for (int off = 32; off; off >>= 1) {
      const float ov = __shfl_xor(best, off);
      const int oi = __shfl_xor(bi, off);
      if (ov > best || (ov == best && oi < bi)) { best = ov; bi = oi; }
    }
    // pack: monotone in dist (f32>=0), ~idx -> max picks smallest index
    if ((t & 63) == 0) {
      sred[t >> 6] = ((unsigned long long)(unsigned int)__float_as_int(best) << 32) |
                     (unsigned int)~(unsigned int)bi;
    }
    __syncthreads();

    if (t < 64) {   // wave 0 handles block combine + cross-block sync
      unsigned long long p = sred[t & 3];
#pragma unroll
      for (int off = 1; off < 4; off <<= 1) {
        const unsigned long long o = __shfl_xor(p, off);
        if (o > p) p = o;
      }
      // p = this block's pack (identical in lanes 0-3)
      if (t == 0) {
        __hip_atomic_store(&bslot[j * NBLK + q], p, __ATOMIC_RELAXED,
                           __HIP_MEMORY_SCOPE_AGENT);
      }
      unsigned long long rp = 0;
      if (t < NBLK) {
        do {
          rp = __hip_atomic_load(&bslot[j * NBLK + t], __ATOMIC_RELAXED,
                                 __HIP_MEMORY_SCOPE_AGENT);
        } while (rp == 0ull);
      }
#pragma unroll
      for (int off = 1; off < 4; off <<= 1) {
        const unsigned long long o = __shfl_xor(rp, off);
        if (o > rp) rp = o;
      }
      if (t == 0) {
        const int gi = (int)~(unsigned int)(rp & 0xffffffffull);
        const float* cp = base + 3 * (size_t)gi;
        const float ncx = cp[0], ncy = cp[1], ncz = cp[2];
        bc = make_float4(ncx, ncy, ncz, 0.f);
        if (q == 0) { qb[3 * j + 0] = ncx; qb[3 * j + 1] = ncy; qb[3 * j + 2] = ncz; }
      }
    }
    __syncthreads();
    cx = bc.x; cy = bc.y; cz = bc.z;
  }
}

// ---------------------------------------------------------------------------
// Kernel 2: fourier positional embedding + 2-layer MLP, fused. (unchanged)
// ---------------------------------------------------------------------------
__global__ __launch_bounds__(256) void embed_mlp_kernel(
    const float* __restrict__ qxyz, const float* __restrict__ pcmin,
    const float* __restrict__ pcmax, const float* __restrict__ G,
    const float* __restrict__ W1, const float* __restrict__ b1,
    const float* __restrict__ W2, const float* __restrict__ b2,
    float* __restrict__ out) {
  const int b = blockIdx.x >> 2;
  const int n0 = (blockIdx.x & 3) * NT;
  const int tid = threadIdx.x;
  const int ty = tid >> 4, tx = tid & 15;

  __shared__ __align__(16) float P[DD][NT + 4];   // pos
  __shared__ __align__(16) float H[DD][NT + 4];   // hidden
  __shared__ __align__(16) float Wl[64][NT + 4];  // W tile (transposed)
  __shared__ float snorm[NT][3];

  if (tid < NT) {
    const int n = n0 + tid;
    const float qx = qxyz[(size_t)b * (NQ * 3) + 3 * n + 0];
    const float qy = qxyz[(size_t)b * (NQ * 3) + 3 * n + 1];
    const float qz = qxyz[(size_t)b * (NQ * 3) + 3 * n + 2];
    snorm[tid][0] = (qx - pcmin[3 * b + 0]) / (pcmax[3 * b + 0] - pcmin[3 * b + 0]);
    snorm[tid][1] = (qy - pcmin[3 * b + 1]) / (pcmax[3 * b + 1] - pcmin[3 * b + 1]);
    snorm[tid][2] = (qz - pcmin[3 * b + 2]) / (pcmax[3 * b + 2] - pcmin[3 * b + 2]);
  }
  __syncthreads();

  {
    const int nn = tid & 63;
    const int fg = tid >> 6;   // 0..3
    const float nx = snorm[nn][0], ny = snorm[nn][1], nz = snorm[nn][2];
#pragma unroll 4
    for (int ff = 0; ff < 32; ++ff) {
      const int f = fg * 32 + ff;
      const float s = nx * G[f] + ny * G[128 + f] + nz * G[256 + f];
      const float proj = 6.28318530717958647692f * s;
      P[f][nn] = sinf(proj);
      P[f + 128][nn] = cosf(proj);
    }
  }

  for (int layer = 0; layer < 2; ++layer) {
    const float* W = layer ? W2 : W1;
    const float* bias = layer ? b2 : b1;
    const float (*src)[NT + 4] = layer ? H : P;

    for (int dt = 0; dt < 4; ++dt) {
      float acc[4][4] = {};
      for (int kt = 0; kt < 4; ++kt) {
        __syncthreads();
        {  // stage W tile transposed: Wl[c][d] = W[dt*64+d][kt*64+c]
          const int r = tid >> 2;
          const int cb = (tid & 3) * 16;
          const float* wrow = W + (size_t)(dt * 64 + r) * DD + kt * 64 + cb;
#pragma unroll
          for (int i = 0; i < 4; ++i) {
            const float4 v = *(const float4*)(wrow + 4 * i);
            Wl[cb + 4 * i + 0][r] = v.x;
            Wl[cb + 4 * i + 1][r] = v.y;
            Wl[cb + 4 * i + 2][r] = v.z;
            Wl[cb + 4 * i + 3][r] = v.w;
          }
        }
        __syncthreads();
#pragma unroll 8
        for (int cc = 0; cc < 64; ++cc) {
          const float4 a = *(const float4*)&Wl[cc][ty * 4];
          const float4 p4 = *(const float4*)&src[kt * 64 + cc][tx * 4];
          acc[0][0] = fmaf(a.x, p4.x, acc[0][0]);
          acc[0][1] = fmaf(a.x, p4.y, acc[0][1]);
          acc[0][2] = fmaf(a.x, p4.z, acc[0][2]);
          acc[0][3] = fmaf(a.x, p4.w, acc[0][3]);
          acc[1][0] = fmaf(a.y, p4.x, acc[1][0]);
          acc[1][1] = fmaf(a.y, p4.y, acc[1][1]);
          acc[1][2] = fmaf(a.y, p4.z, acc[1][2]);
          acc[1][3] = fmaf(a.y, p4.w, acc[1][3]);
          acc[2][0] = fmaf(a.z, p4.x, acc[2][0]);
          acc[2][1] = fmaf(a.z, p4.y, acc[2][1]);
          acc[2][2] = fmaf(a.z, p4.z, acc[2][2]);
          acc[2][3] = fmaf(a.z, p4.w, acc[2][3]);
          acc[3][0] = fmaf(a.w, p4.x, acc[3][0]);
          acc[3][1] = fmaf(a.w, p4.y, acc[3][1]);
          acc[3][2] = fmaf(a.w, p4.z, acc[3][2]);
          acc[3][3] = fmaf(a.w, p4.w, acc[3][3]);
        }
      }
      if (layer == 0) {
#pragma unroll
        for (int i = 0; i < 4; ++i) {
          const float bv = bias[dt * 64 + ty * 4 + i];
          float4 h;
          h.x = fmaxf(acc[i][0] + bv, 0.f);
          h.y = fmaxf(acc[i][1] + bv, 0.f);
          h.z = fmaxf(acc[i][2] + bv, 0.f);
          h.w = fmaxf(acc[i][3] + bv, 0.f);
          *(float4*)&H[dt * 64 + ty * 4 + i][tx * 4] = h;
        }
      } else {
        float* ob = out + (size_t)b * (DD * NQ);
#pragma unroll
        for (int i = 0; i < 4; ++i) {
          const float bv = bias[dt * 64 + ty * 4 + i];
          float4 h;
          h.x = fmaxf(acc[i][0] + bv, 0.f);
          h.y = fmaxf(acc[i][1] + bv, 0.f);
          h.z = fmaxf(acc[i][2] + bv, 0.f);
          h.w = fmaxf(acc[i][3] + bv, 0.f);
          *(float4*)(ob + (size_t)(dt * 64 + ty * 4 + i) * NQ + n0 + tx * 4) = h;
        }
      }
    }
  }
}

extern "C" void kernel_launch(void* const* d_in, const int* in_sizes, int n_in,
                              void* d_out, int out_size, void* d_ws, size_t ws_size,
                              hipStream_t stream) {
  (void)in_sizes; (void)n_in; (void)ws_size; (void)out_size;
  const float* xyz   = (const float*)d_in[0];
  const float* pcmin = (const float*)d_in[1];
  const float* pcmax = (const float*)d_in[2];
  const float* G     = (const float*)d_in[3];
  const float* W1    = (const float*)d_in[4];
  const float* b1    = (const float*)d_in[5];
  const float* W2    = (const float*)d_in[6];
  const float* b2    = (const float*)d_in[7];

  float* qxyz  = (float*)d_out;                       // [64][256][3]
  float* embed = qxyz + (size_t)B_BATCH * NQ * 3;     // [64][256][256]

  unsigned long long* gslot = (unsigned long long*)d_ws;

  // clear sync slots every launch (deterministic across graph replays)
  hipMemsetAsync(d_ws, 0, WS_CLEAR_BYTES, stream);

  hipLaunchKernelGGL(fps_kernel, dim3(B_BATCH * NBLK), dim3(FPS_T), 0, stream,
                     xyz, qxyz, gslot);
  hipLaunchKernelGGL(embed_mlp_kernel, dim3(B_BATCH * 4), dim3(256), 0, stream,
                     qxyz, pcmin, pcmax, G, W1, b1, W2, b2, embed);
}

// Round 11
// 624.946 us; speedup vs baseline: 3.9340x; 1.0049x over previous
//
#include <hip/hip_runtime.h>

#define FPS_N 32768
#define FPS_T 256          // threads per block
#define NBLK 4             // blocks per batch
#define PPB (FPS_N / NBLK) // 8192 points per block
#define PPT (PPB / FPS_T)  // 32 points per thread
#define NCH (PPT / 4)      // 8 four-point chunks per thread
#define NQ 256
#define DD 256
#define NT 64              // n-tile for MLP kernel
#define B_BATCH 64

// d_ws: u64 slot[64][256][4] = 512 KB, zeroed per launch
#define WS_CLEAR_BYTES (B_BATCH * NQ * NBLK * 8)

// ---------------------------------------------------------------------------
// Kernel 1: furthest point sampling, FOUR blocks (256 thr) per batch.
// R10 lesson: single-arg waves_per_eu(1) is only a MINIMUM — the scheduler
// still targets high occupancy and spills C to scratch (VGPR=76, 545us).
// waves_per_eu(1,1) pins min=max=1 wave/EU: budget AND scheduler pressure
// target = 256 VGPR, so coords (96) + dist (32) + misc (~25) stay resident.
// amdgpu_num_vgpr(256) is belt-and-suspenders. asm pin kept (forbids remat).
// Cross-block combine per round: ONE relaxed u64 store per block into its
// own slot (pack = distbits<<32 | ~idx: monotone for f32>=0, ~idx gives
// smallest-index tie-break = jnp.argmax), wave-0 lanes 0-3 poll the 4 slots
// in parallel, butterfly-max. Store-before-poll => deadlock-free; 256 blocks
// on 256 CUs all co-resident (1 block/CU).
// Arithmetic matches numpy bitwise: sub, mul, add (no FMA), fminf.
// ---------------------------------------------------------------------------
__global__ __attribute__((amdgpu_flat_work_group_size(FPS_T, FPS_T),
                          amdgpu_waves_per_eu(1, 1),
                          amdgpu_num_vgpr(256)))
void fps_kernel(const float* __restrict__ xyz, float* __restrict__ qout,
                unsigned long long* __restrict__ gslot) {
  const int gid = blockIdx.x;
  const int xcd = gid & 7;          // round-robin dispatch: block i -> XCD i%8
  const int s = gid >> 3;
  const int b = xcd + 8 * (s >> 2); // all 4 quarters of batch b on same XCD
  const int q = s & 3;
  const int t = threadIdx.x;

  const float* __restrict__ base = xyz + (size_t)b * (FPS_N * 3);
  const float4* __restrict__ base4 =
      (const float4*)(base + (size_t)q * PPB * 3) + (size_t)t * (PPT * 3 / 4);
  float* qb = qout + (size_t)b * (NQ * 3);
  unsigned long long* bslot = gslot + (size_t)b * (NQ * NBLK);

  __shared__ unsigned long long sred[FPS_T / 64];
  __shared__ float4 bc;   // broadcast: cx, cy, cz

  // persistent registers: coords 24 float4 = 96 VGPR, dist 8 float4 = 32 VGPR
  float4 C[PPT * 3 / 4];
#pragma unroll
  for (int i = 0; i < PPT * 3 / 4; ++i) C[i] = base4[i];
  // PIN: forbid rematerialization of the loads
#pragma unroll
  for (int i = 0; i < PPT * 3 / 4; ++i) {
    asm volatile("" : "+v"(C[i].x), "+v"(C[i].y), "+v"(C[i].z), "+v"(C[i].w));
  }
  float4 Dst[NCH];
#pragma unroll
  for (int c = 0; c < NCH; ++c) Dst[c] = make_float4(1e10f, 1e10f, 1e10f, 1e10f);

  if (q == 0 && t == 0) { qb[0] = base[0]; qb[1] = base[1]; qb[2] = base[2]; }
  float cx = base[0], cy = base[1], cz = base[2];   // inds[0] == 0

#pragma unroll 1
  for (int j = 1; j < NQ; ++j) {
    float best = -1.0f;
    int bik = 0;

#pragma unroll
    for (int c = 0; c < NCH; ++c) {
      const float4 a4 = C[3 * c + 0];
      const float4 b4 = C[3 * c + 1];
      const float4 c4 = C[3 * c + 2];
      // unpack 12 floats -> 4 points (register renaming, no real ops)
      const float px[4] = {a4.x, a4.w, b4.z, c4.y};
      const float py[4] = {a4.y, b4.x, b4.w, c4.z};
      const float pz[4] = {a4.z, b4.y, c4.x, c4.w};
      const float dold[4] = {Dst[c].x, Dst[c].y, Dst[c].z, Dst[c].w};
      float dnew[4];
#pragma unroll
      for (int i = 0; i < 4; ++i) {
        const float dx = __fsub_rn(px[i], cx);
        const float dy = __fsub_rn(py[i], cy);
        const float dz = __fsub_rn(pz[i], cz);
        // numpy order: (dx^2 + dy^2) + dz^2, no fma
        const float d = __fadd_rn(__fadd_rn(__fmul_rn(dx, dx), __fmul_rn(dy, dy)),
                                  __fmul_rn(dz, dz));
        const float nd = fminf(dold[i], d);
        dnew[i] = nd;
        if (nd > best) { best = nd; bik = c * 4 + i; }  // strict >: first occ.
      }
      Dst[c] = make_float4(dnew[0], dnew[1], dnew[2], dnew[3]);
    }
    int bi = q * PPB + t * PPT + bik;   // global point index

    // wave (64-lane) argmax reduce with first-index tie-break
#pragma unroll
    for (int off = 32; off; off >>= 1) {
      const float ov = __shfl_xor(best, off);
      const int oi = __shfl_xor(bi, off);
      if (ov > best || (ov == best && oi < bi)) { best = ov; bi = oi; }
    }
    // pack: monotone in dist (f32>=0), ~idx -> max picks smallest index
    if ((t & 63) == 0) {
      sred[t >> 6] = ((unsigned long long)(unsigned int)__float_as_int(best) << 32) |
                     (unsigned int)~(unsigned int)bi;
    }
    __syncthreads();

    if (t < 64) {   // wave 0 handles block combine + cross-block sync
      unsigned long long p = sred[t & 3];
#pragma unroll
      for (int off = 1; off < 4; off <<= 1) {
        const unsigned long long o = __shfl_xor(p, off);
        if (o > p) p = o;
      }
      // p = this block's pack (identical in lanes 0-3)
      if (t == 0) {
        __hip_atomic_store(&bslot[j * NBLK + q], p, __ATOMIC_RELAXED,
                           __HIP_MEMORY_SCOPE_AGENT);
      }
      unsigned long long rp = 0;
      if (t < NBLK) {
        do {
          rp = __hip_atomic_load(&bslot[j * NBLK + t], __ATOMIC_RELAXED,
                                 __HIP_MEMORY_SCOPE_AGENT);
        } while (rp == 0ull);
      }
#pragma unroll
      for (int off = 1; off < 4; off <<= 1) {
        const unsigned long long o = __shfl_xor(rp, off);
        if (o > rp) rp = o;
      }
      if (t == 0) {
        const int gi = (int)~(unsigned int)(rp & 0xffffffffull);
        const float* cp = base + 3 * (size_t)gi;
        const float ncx = cp[0], ncy = cp[1], ncz = cp[2];
        bc = make_float4(ncx, ncy, ncz, 0.f);
        if (q == 0) { qb[3 * j + 0] = ncx; qb[3 * j + 1] = ncy; qb[3 * j + 2] = ncz; }
      }
    }
    __syncthreads();
    cx = bc.x; cy = bc.y; cz = bc.z;
  }
}

// ---------------------------------------------------------------------------
// Kernel 2: fourier positional embedding + 2-layer MLP, fused. (unchanged)
// ---------------------------------------------------------------------------
__global__ __launch_bounds__(256) void embed_mlp_kernel(
    const float* __restrict__ qxyz, const float* __restrict__ pcmin,
    const float* __restrict__ pcmax, const float* __restrict__ G,
    const float* __restrict__ W1, const float* __restrict__ b1,
    const float* __restrict__ W2, const float* __restrict__ b2,
    float* __restrict__ out) {
  const int b = blockIdx.x >> 2;
  const int n0 = (blockIdx.x & 3) * NT;
  const int tid = threadIdx.x;
  const int ty = tid >> 4, tx = tid & 15;

  __shared__ __align__(16) float P[DD][NT + 4];   // pos
  __shared__ __align__(16) float H[DD][NT + 4];   // hidden
  __shared__ __align__(16) float Wl[64][NT + 4];  // W tile (transposed)
  __shared__ float snorm[NT][3];

  if (tid < NT) {
    const int n = n0 + tid;
    const float qx = qxyz[(size_t)b * (NQ * 3) + 3 * n + 0];
    const float qy = qxyz[(size_t)b * (NQ * 3) + 3 * n + 1];
    const float qz = qxyz[(size_t)b * (NQ * 3) + 3 * n + 2];
    snorm[tid][0] = (qx - pcmin[3 * b + 0]) / (pcmax[3 * b + 0] - pcmin[3 * b + 0]);
    snorm[tid][1] = (qy - pcmin[3 * b + 1]) / (pcmax[3 * b + 1] - pcmin[3 * b + 1]);
    snorm[tid][2] = (qz - pcmin[3 * b + 2]) / (pcmax[3 * b + 2] - pcmin[3 * b + 2]);
  }
  __syncthreads();

  {
    const int nn = tid & 63;
    const int fg = tid >> 6;   // 0..3
    const float nx = snorm[nn][0], ny = snorm[nn][1], nz = snorm[nn][2];
#pragma unroll 4
    for (int ff = 0; ff < 32; ++ff) {
      const int f = fg * 32 + ff;
      const float s = nx * G[f] + ny * G[128 + f] + nz * G[256 + f];
      const float proj = 6.28318530717958647692f * s;
      P[f][nn] = sinf(proj);
      P[f + 128][nn] = cosf(proj);
    }
  }

  for (int layer = 0; layer < 2; ++layer) {
    const float* W = layer ? W2 : W1;
    const float* bias = layer ? b2 : b1;
    const float (*src)[NT + 4] = layer ? H : P;

    for (int dt = 0; dt < 4; ++dt) {
      float acc[4][4] = {};
      for (int kt = 0; kt < 4; ++kt) {
        __syncthreads();
        {  // stage W tile transposed: Wl[c][d] = W[dt*64+d][kt*64+c]
          const int r = tid >> 2;
          const int cb = (tid & 3) * 16;
          const float* wrow = W + (size_t)(dt * 64 + r) * DD + kt * 64 + cb;
#pragma unroll
          for (int i = 0; i < 4; ++i) {
            const float4 v = *(const float4*)(wrow + 4 * i);
            Wl[cb + 4 * i + 0][r] = v.x;
            Wl[cb + 4 * i + 1][r] = v.y;
            Wl[cb + 4 * i + 2][r] = v.z;
            Wl[cb + 4 * i + 3][r] = v.w;
          }
        }
        __syncthreads();
#pragma unroll 8
        for (int cc = 0; cc < 64; ++cc) {
          const float4 a = *(const float4*)&Wl[cc][ty * 4];
          const float4 p4 = *(const float4*)&src[kt * 64 + cc][tx * 4];
          acc[0][0] = fmaf(a.x, p4.x, acc[0][0]);
          acc[0][1] = fmaf(a.x, p4.y, acc[0][1]);
          acc[0][2] = fmaf(a.x, p4.z, acc[0][2]);
          acc[0][3] = fmaf(a.x, p4.w, acc[0][3]);
          acc[1][0] = fmaf(a.y, p4.x, acc[1][0]);
          acc[1][1] = fmaf(a.y, p4.y, acc[1][1]);
          acc[1][2] = fmaf(a.y, p4.z, acc[1][2]);
          acc[1][3] = fmaf(a.y, p4.w, acc[1][3]);
          acc[2][0] = fmaf(a.z, p4.x, acc[2][0]);
          acc[2][1] = fmaf(a.z, p4.y, acc[2][1]);
          acc[2][2] = fmaf(a.z, p4.z, acc[2][2]);
          acc[2][3] = fmaf(a.z, p4.w, acc[2][3]);
          acc[3][0] = fmaf(a.w, p4.x, acc[3][0]);
          acc[3][1] = fmaf(a.w, p4.y, acc[3][1]);
          acc[3][2] = fmaf(a.w, p4.z, acc[3][2]);
          acc[3][3] = fmaf(a.w, p4.w, acc[3][3]);
        }
      }
      if (layer == 0) {
#pragma unroll
        for (int i = 0; i < 4; ++i) {
          const float bv = bias[dt * 64 + ty * 4 + i];
          float4 h;
          h.x = fmaxf(acc[i][0] + bv, 0.f);
          h.y = fmaxf(acc[i][1] + bv, 0.f);
          h.z = fmaxf(acc[i][2] + bv, 0.f);
          h.w = fmaxf(acc[i][3] + bv, 0.f);
          *(float4*)&H[dt * 64 + ty * 4 + i][tx * 4] = h;
        }
      } else {
        float* ob = out + (size_t)b * (DD * NQ);
#pragma unroll
        for (int i = 0; i < 4; ++i) {
          const float bv = bias[dt * 64 + ty * 4 + i];
          float4 h;
          h.x = fmaxf(acc[i][0] + bv, 0.f);
          h.y = fmaxf(acc[i][1] + bv, 0.f);
          h.z = fmaxf(acc[i][2] + bv, 0.f);
          h.w = fmaxf(acc[i][3] + bv, 0.f);
          *(float4*)(ob + (size_t)(dt * 64 + ty * 4 + i) * NQ + n0 + tx * 4) = h;
        }
      }
    }
  }
}

extern "C" void kernel_launch(void* const* d_in, const int* in_sizes, int n_in,
                              void* d_out, int out_size, void* d_ws, size_t ws_size,
                              hipStream_t stream) {
  (void)in_sizes; (void)n_in; (void)ws_size; (void)out_size;
  const float* xyz   = (const float*)d_in[0];
  const float* pcmin = (const float*)d_in[1];
  const float* pcmax = (const float*)d_in[2];
  const float* G     = (const float*)d_in[3];
  const float* W1    = (const float*)d_in[4];
  const float* b1    = (const float*)d_in[5];
  const float* W2    = (const float*)d_in[6];
  const float* b2    = (const float*)d_in[7];

  float* qxyz  = (float*)d_out;                       // [64][256][3]
  float* embed = qxyz + (size_t)B_BATCH * NQ * 3;     // [64][256][256]

  unsigned long long* gslot = (unsigned long long*)d_ws;

  // clear sync slots every launch (deterministic across graph replays)
  hipMemsetAsync(d_ws, 0, WS_CLEAR_BYTES, stream);

  hipLaunchKernelGGL(fps_kernel, dim3(B_BATCH * NBLK), dim3(FPS_T), 0, stream,
                     xyz, qxyz, gslot);
  hipLaunchKernelGGL(embed_mlp_kernel, dim3(B_BATCH * 4), dim3(256), 0, stream,
                     qxyz, pcmin, pcmax, G, W1, b1, W2, b2, embed);
}

// Round 12
// 582.420 us; speedup vs baseline: 4.2212x; 1.0730x over previous
//
#include <hip/hip_runtime.h>

#define FPS_N 32768
#define FPS_T 256          // threads per block
#define NBLK 8             // blocks per batch
#define PPB (FPS_N / NBLK) // 4096 points per block
#define PPT (PPB / FPS_T)  // 16 points per thread
#define NCH (PPT / 4)      // 4 four-point chunks per thread
#define NQ 256
#define DD 256
#define NT 64              // n-tile for MLP kernel
#define B_BATCH 64

// d_ws: u64 slot[64][256][8] = 1 MB, zeroed per launch
#define WS_CLEAR_BYTES (B_BATCH * NQ * NBLK * 8)

// ---------------------------------------------------------------------------
// Kernel 1: furthest point sampling, EIGHT blocks (256 thr) per batch.
// R11 lesson: at PPT=32 demand (~155 VGPR) the allocator grants only 132 ->
// residual spill, 545us flat across R9-R11. Fix by SHRINKING demand:
// PPT=16 -> coords 12xfloat4=48 + dist 4xfloat4=16 + misc ~25 = ~90 VGPR,
// comfortably inside the 128 budget of waves_per_eu(2,2). No spill, no remat.
// 512 blocks = 2/CU, co-residency trivial (8 waves/CU of 32).
// Cross-block combine per round (proven R9): ONE relaxed u64 store per block
// (pack = distbits<<32 | ~idx; monotone for f32>=0; ~idx = smallest-index
// tie-break = jnp.argmax), wave-0 lanes 0-7 poll the 8 slots in parallel,
// 3-step butterfly-max. Store-before-poll => deadlock-free.
// Batch's 8 blocks land on one XCD (gid stride 8 round-robin).
// Arithmetic matches numpy bitwise: sub, mul, add (no FMA), fminf.
// ---------------------------------------------------------------------------
__global__ __attribute__((amdgpu_flat_work_group_size(FPS_T, FPS_T),
                          amdgpu_waves_per_eu(2, 2)))
void fps_kernel(const float* __restrict__ xyz, float* __restrict__ qout,
                unsigned long long* __restrict__ gslot) {
  const int gid = blockIdx.x;
  const int xcd = gid & 7;          // round-robin dispatch: block i -> XCD i%8
  const int s = gid >> 3;
  const int b = xcd + 8 * (s >> 3); // all 8 eighths of batch b on same XCD
  const int q = s & 7;
  const int t = threadIdx.x;

  const float* __restrict__ base = xyz + (size_t)b * (FPS_N * 3);
  const float4* __restrict__ base4 =
      (const float4*)(base + (size_t)q * PPB * 3) + (size_t)t * (PPT * 3 / 4);
  float* qb = qout + (size_t)b * (NQ * 3);
  unsigned long long* bslot = gslot + (size_t)b * (NQ * NBLK);

  __shared__ unsigned long long sred[FPS_T / 64];
  __shared__ float4 bc;   // broadcast: cx, cy, cz

  // persistent registers: coords 12 float4 = 48 VGPR, dist 4 float4 = 16 VGPR
  float4 C[PPT * 3 / 4];
#pragma unroll
  for (int i = 0; i < PPT * 3 / 4; ++i) C[i] = base4[i];
  // PIN: forbid rematerialization of the loads
#pragma unroll
  for (int i = 0; i < PPT * 3 / 4; ++i) {
    asm volatile("" : "+v"(C[i].x), "+v"(C[i].y), "+v"(C[i].z), "+v"(C[i].w));
  }
  float4 Dst[NCH];
#pragma unroll
  for (int c = 0; c < NCH; ++c) Dst[c] = make_float4(1e10f, 1e10f, 1e10f, 1e10f);

  if (q == 0 && t == 0) { qb[0] = base[0]; qb[1] = base[1]; qb[2] = base[2]; }
  float cx = base[0], cy = base[1], cz = base[2];   // inds[0] == 0

#pragma unroll 1
  for (int j = 1; j < NQ; ++j) {
    float best = -1.0f;
    int bik = 0;

#pragma unroll
    for (int c = 0; c < NCH; ++c) {
      const float4 a4 = C[3 * c + 0];
      const float4 b4 = C[3 * c + 1];
      const float4 c4 = C[3 * c + 2];
      // unpack 12 floats -> 4 points (register renaming, no real ops)
      const float px[4] = {a4.x, a4.w, b4.z, c4.y};
      const float py[4] = {a4.y, b4.x, b4.w, c4.z};
      const float pz[4] = {a4.z, b4.y, c4.x, c4.w};
      const float dold[4] = {Dst[c].x, Dst[c].y, Dst[c].z, Dst[c].w};
      float dnew[4];
#pragma unroll
      for (int i = 0; i < 4; ++i) {
        const float dx = __fsub_rn(px[i], cx);
        const float dy = __fsub_rn(py[i], cy);
        const float dz = __fsub_rn(pz[i], cz);
        // numpy order: (dx^2 + dy^2) + dz^2, no fma
        const float d = __fadd_rn(__fadd_rn(__fmul_rn(dx, dx), __fmul_rn(dy, dy)),
                                  __fmul_rn(dz, dz));
        const float nd = fminf(dold[i], d);
        dnew[i] = nd;
        if (nd > best) { best = nd; bik = c * 4 + i; }  // strict >: first occ.
      }
      Dst[c] = make_float4(dnew[0], dnew[1], dnew[2], dnew[3]);
    }
    int bi = q * PPB + t * PPT + bik;   // global point index

    // wave (64-lane) argmax reduce with first-index tie-break
#pragma unroll
    for (int off = 32; off; off >>= 1) {
      const float ov = __shfl_xor(best, off);
      const int oi = __shfl_xor(bi, off);
      if (ov > best || (ov == best && oi < bi)) { best = ov; bi = oi; }
    }
    // pack: monotone in dist (f32>=0), ~idx -> max picks smallest index
    if ((t & 63) == 0) {
      sred[t >> 6] = ((unsigned long long)(unsigned int)__float_as_int(best) << 32) |
                     (unsigned int)~(unsigned int)bi;
    }
    __syncthreads();

    if (t < 64) {   // wave 0 handles block combine + cross-block sync
      unsigned long long p = sred[t & 3];
#pragma unroll
      for (int off = 1; off < 4; off <<= 1) {
        const unsigned long long o = __shfl_xor(p, off);
        if (o > p) p = o;
      }
      // p = this block's pack (identical in lanes 0-7)
      if (t == 0) {
        __hip_atomic_store(&bslot[j * NBLK + q], p, __ATOMIC_RELAXED,
                           __HIP_MEMORY_SCOPE_AGENT);
      }
      unsigned long long rp = 0;
      if (t < NBLK) {
        do {
          rp = __hip_atomic_load(&bslot[j * NBLK + t], __ATOMIC_RELAXED,
                                 __HIP_MEMORY_SCOPE_AGENT);
        } while (rp == 0ull);
      }
#pragma unroll
      for (int off = 1; off < NBLK; off <<= 1) {
        const unsigned long long o = __shfl_xor(rp, off);
        if (o > rp) rp = o;
      }
      if (t == 0) {
        const int gi = (int)~(unsigned int)(rp & 0xffffffffull);
        const float* cp = base + 3 * (size_t)gi;
        const float ncx = cp[0], ncy = cp[1], ncz = cp[2];
        bc = make_float4(ncx, ncy, ncz, 0.f);
        if (q == 0) { qb[3 * j + 0] = ncx; qb[3 * j + 1] = ncy; qb[3 * j + 2] = ncz; }
      }
    }
    __syncthreads();
    cx = bc.x; cy = bc.y; cz = bc.z;
  }
}

// ---------------------------------------------------------------------------
// Kernel 2: fourier positional embedding + 2-layer MLP, fused. (unchanged)
// ---------------------------------------------------------------------------
__global__ __launch_bounds__(256) void embed_mlp_kernel(
    const float* __restrict__ qxyz, const float* __restrict__ pcmin,
    const float* __restrict__ pcmax, const float* __restrict__ G,
    const float* __restrict__ W1, const float* __restrict__ b1,
    const float* __restrict__ W2, const float* __restrict__ b2,
    float* __restrict__ out) {
  const int b = blockIdx.x >> 2;
  const int n0 = (blockIdx.x & 3) * NT;
  const int tid = threadIdx.x;
  const int ty = tid >> 4, tx = tid & 15;

  __shared__ __align__(16) float P[DD][NT + 4];   // pos
  __shared__ __align__(16) float H[DD][NT + 4];   // hidden
  __shared__ __align__(16) float Wl[64][NT + 4];  // W tile (transposed)
  __shared__ float snorm[NT][3];

  if (tid < NT) {
    const int n = n0 + tid;
    const float qx = qxyz[(size_t)b * (NQ * 3) + 3 * n + 0];
    const float qy = qxyz[(size_t)b * (NQ * 3) + 3 * n + 1];
    const float qz = qxyz[(size_t)b * (NQ * 3) + 3 * n + 2];
    snorm[tid][0] = (qx - pcmin[3 * b + 0]) / (pcmax[3 * b + 0] - pcmin[3 * b + 0]);
    snorm[tid][1] = (qy - pcmin[3 * b + 1]) / (pcmax[3 * b + 1] - pcmin[3 * b + 1]);
    snorm[tid][2] = (qz - pcmin[3 * b + 2]) / (pcmax[3 * b + 2] - pcmin[3 * b + 2]);
  }
  __syncthreads();

  {
    const int nn = tid & 63;
    const int fg = tid >> 6;   // 0..3
    const float nx = snorm[nn][0], ny = snorm[nn][1], nz = snorm[nn][2];
#pragma unroll 4
    for (int ff = 0; ff < 32; ++ff) {
      const int f = fg * 32 + ff;
      const float s = nx * G[f] + ny * G[128 + f] + nz * G[256 + f];
      const float proj = 6.28318530717958647692f * s;
      P[f][nn] = sinf(proj);
      P[f + 128][nn] = cosf(proj);
    }
  }

  for (int layer = 0; layer < 2; ++layer) {
    const float* W = layer ? W2 : W1;
    const float* bias = layer ? b2 : b1;
    const float (*src)[NT + 4] = layer ? H : P;

    for (int dt = 0; dt < 4; ++dt) {
      float acc[4][4] = {};
      for (int kt = 0; kt < 4; ++kt) {
        __syncthreads();
        {  // stage W tile transposed: Wl[c][d] = W[dt*64+d][kt*64+c]
          const int r = tid >> 2;
          const int cb = (tid & 3) * 16;
          const float* wrow = W + (size_t)(dt * 64 + r) * DD + kt * 64 + cb;
#pragma unroll
          for (int i = 0; i < 4; ++i) {
            const float4 v = *(const float4*)(wrow + 4 * i);
            Wl[cb + 4 * i + 0][r] = v.x;
            Wl[cb + 4 * i + 1][r] = v.y;
            Wl[cb + 4 * i + 2][r] = v.z;
            Wl[cb + 4 * i + 3][r] = v.w;
          }
        }
        __syncthreads();
#pragma unroll 8
        for (int cc = 0; cc < 64; ++cc) {
          const float4 a = *(const float4*)&Wl[cc][ty * 4];
          const float4 p4 = *(const float4*)&src[kt * 64 + cc][tx * 4];
          acc[0][0] = fmaf(a.x, p4.x, acc[0][0]);
          acc[0][1] = fmaf(a.x, p4.y, acc[0][1]);
          acc[0][2] = fmaf(a.x, p4.z, acc[0][2]);
          acc[0][3] = fmaf(a.x, p4.w, acc[0][3]);
          acc[1][0] = fmaf(a.y, p4.x, acc[1][0]);
          acc[1][1] = fmaf(a.y, p4.y, acc[1][1]);
          acc[1][2] = fmaf(a.y, p4.z, acc[1][2]);
          acc[1][3] = fmaf(a.y, p4.w, acc[1][3]);
          acc[2][0] = fmaf(a.z, p4.x, acc[2][0]);
          acc[2][1] = fmaf(a.z, p4.y, acc[2][1]);
          acc[2][2] = fmaf(a.z, p4.z, acc[2][2]);
          acc[2][3] = fmaf(a.z, p4.w, acc[2][3]);
          acc[3][0] = fmaf(a.w, p4.x, acc[3][0]);
          acc[3][1] = fmaf(a.w, p4.y, acc[3][1]);
          acc[3][2] = fmaf(a.w, p4.z, acc[3][2]);
          acc[3][3] = fmaf(a.w, p4.w, acc[3][3]);
        }
      }
      if (layer == 0) {
#pragma unroll
        for (int i = 0; i < 4; ++i) {
          const float bv = bias[dt * 64 + ty * 4 + i];
          float4 h;
          h.x = fmaxf(acc[i][0] + bv, 0.f);
          h.y = fmaxf(acc[i][1] + bv, 0.f);
          h.z = fmaxf(acc[i][2] + bv, 0.f);
          h.w = fmaxf(acc[i][3] + bv, 0.f);
          *(float4*)&H[dt * 64 + ty * 4 + i][tx * 4] = h;
        }
      } else {
        float* ob = out + (size_t)b * (DD * NQ);
#pragma unroll
        for (int i = 0; i < 4; ++i) {
          const float bv = bias[dt * 64 + ty * 4 + i];
          float4 h;
          h.x = fmaxf(acc[i][0] + bv, 0.f);
          h.y = fmaxf(acc[i][1] + bv, 0.f);
          h.z = fmaxf(acc[i][2] + bv, 0.f);
          h.w = fmaxf(acc[i][3] + bv, 0.f);
          *(float4*)(ob + (size_t)(dt * 64 + ty * 4 + i) * NQ + n0 + tx * 4) = h;
        }
      }
    }
  }
}

extern "C" void kernel_launch(void* const* d_in, const int* in_sizes, int n_in,
                              void* d_out, int out_size, void* d_ws, size_t ws_size,
                              hipStream_t stream) {
  (void)in_sizes; (void)n_in; (void)ws_size; (void)out_size;
  const float* xyz   = (const float*)d_in[0];
  const float* pcmin = (const float*)d_in[1];
  const float* pcmax = (const float*)d_in[2];
  const float* G     = (const float*)d_in[3];
  const float* W1    = (const float*)d_in[4];
  const float* b1    = (const float*)d_in[5];
  const float* W2    = (const float*)d_in[6];
  const float* b2    = (const float*)d_in[7];

  float* qxyz  = (float*)d_out;                       // [64][256][3]
  float* embed = qxyz + (size_t)B_BATCH * NQ * 3;     // [64][256][256]

  unsigned long long* gslot = (unsigned long long*)d_ws;

  // clear sync slots every launch (deterministic across graph replays)
  hipMemsetAsync(d_ws, 0, WS_CLEAR_BYTES, stream);

  hipLaunchKernelGGL(fps_kernel, dim3(B_BATCH * NBLK), dim3(FPS_T), 0, stream,
                     xyz, qxyz, gslot);
  hipLaunchKernelGGL(embed_mlp_kernel, dim3(B_BATCH * 4), dim3(256), 0, stream,
                     qxyz, pcmin, pcmax, G, W1, b1, W2, b2, embed);
}